// Round 11
// baseline (178.497 us; speedup 1.0000x reference)
//
#include <hip/hip_runtime.h>
#include <hip/hip_bf16.h>
#include <math.h>

#define NLOOP 8
#define BB 8
#define LLEN 2048
#define DD 768
#define VV 50288
#define HALT 50277
#define EPSF 1e-5f

#define BN 64
#define BKK 32
#define KSTEPS (DD / BKK)              // 24
#define NBLK ((VV + BN - 1) / BN)      // 786
#define PFD 4                          // KSTEPS % PFD == 0

typedef short bf16x8 __attribute__((ext_vector_type(8)));
typedef float f32x4 __attribute__((ext_vector_type(4)));

// lgkm-only barrier: ds ops drained, global loads stay in flight (counted vmcnt at use).
#define LGKM_BARRIER() asm volatile("s_waitcnt lgkmcnt(0)\n\ts_barrier" ::: "memory")

__device__ __forceinline__ unsigned short f32_to_bf16(float f) {
    unsigned u = __builtin_bit_cast(unsigned, f);
    unsigned r = (u + 0x7FFFu + ((u >> 16) & 1u)) >> 16;
    return (unsigned short)r;
}

// ---------------- Kernel 1: gather + RMSNorm + target logits ----------------
__global__ __launch_bounds__(256) void k_prep(
    const float* __restrict__ x, const float* __restrict__ res,
    const float* __restrict__ nw, const float* __restrict__ W,
    const int* __restrict__ ans_starts, const int* __restrict__ chain_targets,
    const int* __restrict__ chain_lens,
    unsigned short* __restrict__ hbf, float* __restrict__ tgt_logit,
    unsigned int* __restrict__ counters)
{
    if (blockIdx.x == 0 && threadIdx.x == 0) { counters[0] = 0u; counters[1] = 0u; }

    int lb = blockIdx.x, l = lb >> 3, b = lb & 7;
    int tid = threadIdx.x, lane = tid & 63, wave = tid >> 6;
    int as = ans_starts[b];
    int pos = as - 1;
    pos = pos < 0 ? 0 : (pos > LLEN - 1 ? LLEN - 1 : pos);
    size_t base = ((size_t)lb * LLEN + (size_t)pos) * DD;

    float hv[3];
    float ss = 0.f;
#pragma unroll
    for (int i = 0; i < 3; ++i) {
        int d = tid + i * 256;
        float v = x[base + d] + res[base + d];
        hv[i] = v;
        ss += v * v;
    }
#pragma unroll
    for (int off = 32; off; off >>= 1) ss += __shfl_down(ss, off);
    __shared__ float red[4];
    __shared__ float bc;
    if (lane == 0) red[wave] = ss;
    __syncthreads();
    if (tid == 0) bc = red[0] + red[1] + red[2] + red[3];
    __syncthreads();
    float rs = rsqrtf(bc / (float)DD + EPSF);

    int cl = chain_lens[b];
    int tix = l < cl - 1 ? l : cl - 1;
    int tgt = chain_targets[b * NLOOP + tix];
    bool tok = (tgt >= 0) && (tgt < VV);

    float dp = 0.f;
#pragma unroll
    for (int i = 0; i < 3; ++i) {
        int d = tid + i * 256;
        float h = hv[i] * rs * nw[d];
        hbf[(size_t)lb * DD + d] = f32_to_bf16(h);
        if (tok) dp += h * W[(size_t)tgt * DD + d];
    }
#pragma unroll
    for (int off = 32; off; off >>= 1) dp += __shfl_down(dp, off);
    __syncthreads();
    if (lane == 0) red[wave] = dp;
    __syncthreads();
    if (tid == 0) tgt_logit[lb] = red[0] + red[1] + red[2] + red[3];
}

// ------ Kernel 2: A-in-regs MFMA logits + ticketed combine + epilogue -------
// GEMM body = R5 (57.8us trunk) with R10's conflict-free XOR-swizzled B-tile:
// row = 32 shorts (64B); write unit uw = j2^((r1>>1)&3), read unit
// ur = q^((c>>1)&3) -- both phase-exact on 32 banks (8-lane phase covers 32
// distinct banks; bank audit in R10/R11 notes). One ds_write_b128 per thread
// per K-step. lgkm-only barrier; 4-deep counted-vmcnt prefetch.
// Tail: ticket via counters[0]; last 64 tickets combine one row each; last
// combiner (counters[1]) runs the scalar epilogue. 3 nodes -> 2.
__global__ __launch_bounds__(256) void k_logits(
    const float* __restrict__ W, const unsigned short* __restrict__ hbf,
    const float* __restrict__ tgt_logit,
    const int* __restrict__ ans_starts, const int* __restrict__ chain_targets,
    const int* __restrict__ chain_lens,
    float* __restrict__ pmax, float* __restrict__ psum, int* __restrict__ parg,
    float* __restrict__ logZ, int* __restrict__ pred,
    unsigned int* __restrict__ counters, float* __restrict__ out)
{
    __shared__ unsigned short Bs[2][64 * 32];   // 4 KB per buffer, 64B rows

    int blk = blockIdx.x;
    int v0 = blk * BN;
    int tid = threadIdx.x;
    int wave = tid >> 6, lane = tid & 63, q = lane >> 4, c = lane & 15;

    // ---- A preload: h row (16*wave + c), k = ks*32 + q*8 + j (L2-hot) ----
    const unsigned short* Ap = hbf + (size_t)(16 * wave + c) * DD + q * 8;
    bf16x8 A[KSTEPS];
#pragma unroll
    for (int ks = 0; ks < KSTEPS; ++ks)
        A[ks] = *(const bf16x8*)(Ap + ks * BKK);

    // ---- B staging: thread (r1=tid>>2, j2=tid&3) loads row r1's 8 f32 ----
    int r1 = tid >> 2, j2 = tid & 3;
    int vB = v0 + r1;
    const float* gB = W + (size_t)(vB < VV ? vB : 0) * DD + j2 * 8;  // clamp; cols masked later

    f32x4 acc[4];
#pragma unroll
    for (int n = 0; n < 4; ++n) acc[n] = (f32x4){0.f, 0.f, 0.f, 0.f};

    const int uw = (j2 ^ ((r1 >> 1) & 3)) * 8;     // swizzled write unit (shorts)
    const int ur = (q ^ ((c >> 1) & 3)) * 8;       // swizzled read unit (shorts)

    auto stage_write = [&](int bufi, const f32x4& ra, const f32x4& rb) {
        bf16x8 v;
        v[0] = (short)f32_to_bf16(ra[0]); v[1] = (short)f32_to_bf16(ra[1]);
        v[2] = (short)f32_to_bf16(ra[2]); v[3] = (short)f32_to_bf16(ra[3]);
        v[4] = (short)f32_to_bf16(rb[0]); v[5] = (short)f32_to_bf16(rb[1]);
        v[6] = (short)f32_to_bf16(rb[2]); v[7] = (short)f32_to_bf16(rb[3]);
        *(bf16x8*)&Bs[bufi][r1 * 32 + uw] = v;
    };
    auto mfma_step = [&](int bufi, int ks) {
        bf16x8 f0 = *(const bf16x8*)&Bs[bufi][(c +  0) * 32 + ur];
        bf16x8 f1 = *(const bf16x8*)&Bs[bufi][(c + 16) * 32 + ur];
        bf16x8 f2 = *(const bf16x8*)&Bs[bufi][(c + 32) * 32 + ur];
        bf16x8 f3 = *(const bf16x8*)&Bs[bufi][(c + 48) * 32 + ur];
        acc[0] = __builtin_amdgcn_mfma_f32_16x16x32_bf16(A[ks], f0, acc[0], 0, 0, 0);
        acc[1] = __builtin_amdgcn_mfma_f32_16x16x32_bf16(A[ks], f1, acc[1], 0, 0, 0);
        acc[2] = __builtin_amdgcn_mfma_f32_16x16x32_bf16(A[ks], f2, acc[2], 0, 0, 0);
        acc[3] = __builtin_amdgcn_mfma_f32_16x16x32_bf16(A[ks], f3, acc[3], 0, 0, 0);
    };

    // 4-deep register pipeline (named sets, static indexing via full unroll)
    f32x4 pa[PFD], pb[PFD];
#pragma unroll
    for (int i = 0; i < PFD; ++i) {
        pa[i] = *(const f32x4*)(gB + i * BKK);
        pb[i] = *(const f32x4*)(gB + i * BKK + 4);
    }

#pragma unroll
    for (int ks = 0; ks < KSTEPS; ++ks) {          // fully unrolled: slots static
        const int slot = ks % PFD;
        const int bufi = ks & 1;
        stage_write(bufi, pa[slot], pb[slot]);
        LGKM_BARRIER();
        if (ks + PFD < KSTEPS) {
            pa[slot] = *(const f32x4*)(gB + (ks + PFD) * BKK);
            pb[slot] = *(const f32x4*)(gB + (ks + PFD) * BKK + 4);
        }
        mfma_step(bufi, ks);
    }

    // ---- wave-internal per-row max / argmax / sumexp over 64 block cols ----
    const float NEGINF = -__builtin_inff();
#pragma unroll
    for (int r = 0; r < 4; ++r) {
        float val = NEGINF; int idx = 0x7fffffff;
#pragma unroll
        for (int n = 0; n < 4; ++n) {
            int colg = v0 + 16 * n + c;
            float v = (colg < VV) ? acc[n][r] : NEGINF;
            if (v > val || (v == val && colg < idx)) { val = v; idx = colg; }
        }
#pragma unroll
        for (int off = 1; off < 16; off <<= 1) {
            float ov = __shfl_xor(val, off);
            int oi = __shfl_xor(idx, off);
            if (ov > val || (ov == val && oi < idx)) { val = ov; idx = oi; }
        }
        float M = val;          // all 16 lanes of the q-group hold the row max
        float e = 0.f;
#pragma unroll
        for (int n = 0; n < 4; ++n) {
            int colg = v0 + 16 * n + c;
            e += (colg < VV) ? __expf(acc[n][r] - M) : 0.f;
        }
#pragma unroll
        for (int off = 1; off < 16; off <<= 1) e += __shfl_xor(e, off);
        if (c == 0) {
            int row = 16 * wave + 4 * q + r;
            pmax[(size_t)row * NBLK + blk] = M;
            psum[(size_t)row * NBLK + blk] = e;
            parg[(size_t)row * NBLK + blk] = idx;
        }
    }

    // ---------------- ticket: last 64 finishers combine one row each --------
    __threadfence();                     // partial writes visible (release)
    __syncthreads();
    __shared__ unsigned int s_old;
    if (tid == 0) s_old = atomicAdd(&counters[0], 1u);
    __syncthreads();
    int crow = (int)s_old - (NBLK - 64);
    if (crow < 0) return;

    if (tid == 0) {
        while (__hip_atomic_load(&counters[0], __ATOMIC_ACQUIRE, __HIP_MEMORY_SCOPE_AGENT) < (unsigned)NBLK)
            __builtin_amdgcn_s_sleep(8);
    }
    __syncthreads();
    __threadfence();                     // acquire: see all blocks' partials

    {
        const float* pm = pmax + (size_t)crow * NBLK;
        const float* ps = psum + (size_t)crow * NBLK;
        const int*   pa2 = parg + (size_t)crow * NBLK;

        float M = NEGINF; int A_ = 0x7fffffff;
        for (int i = tid; i < NBLK; i += 256) {
            float m = pm[i];
            int a = pa2[i];
            if (m > M || (m == M && a < A_)) { M = m; A_ = a; }
        }
#pragma unroll
        for (int off = 1; off < 64; off <<= 1) {
            float ov = __shfl_xor(M, off);
            int oa = __shfl_xor(A_, off);
            if (ov > M || (ov == M && oa < A_)) { M = ov; A_ = oa; }
        }
        __shared__ float sm[4]; __shared__ int sa[4]; __shared__ float ssum[4];
        __shared__ int lastflag;
        if (lane == 0) { sm[wave] = M; sa[wave] = A_; }
        __syncthreads();
        if (tid == 0) {
#pragma unroll
            for (int w = 1; w < 4; ++w)
                if (sm[w] > sm[0] || (sm[w] == sm[0] && sa[w] < sa[0])) { sm[0] = sm[w]; sa[0] = sa[w]; }
        }
        __syncthreads();
        float Mg = sm[0];

        float S = 0.f;
        for (int i = tid; i < NBLK; i += 256)
            S += ps[i] * __expf(pm[i] - Mg);
#pragma unroll
        for (int off = 1; off < 64; off <<= 1) S += __shfl_xor(S, off);
        if (lane == 0) ssum[wave] = S;
        __syncthreads();
        if (tid == 0) {
            float lz = Mg + logf(ssum[0] + ssum[1] + ssum[2] + ssum[3]);
            __hip_atomic_store(&logZ[crow], lz, __ATOMIC_RELAXED, __HIP_MEMORY_SCOPE_AGENT);
            __hip_atomic_store(&pred[crow], sa[0], __ATOMIC_RELAXED, __HIP_MEMORY_SCOPE_AGENT);
            __threadfence();                               // release
            unsigned int old2 = atomicAdd(&counters[1], 1u);
            lastflag = (old2 == 63u) ? 1 : 0;
        }
        __syncthreads();
        if (lastflag == 0) return;

        // ---- very last combiner: scalar epilogue ----
        __threadfence();                                   // acquire
        __shared__ float lzs[64]; __shared__ int prs[64];
        if (tid < 64) {
            lzs[tid] = __hip_atomic_load(&logZ[tid], __ATOMIC_RELAXED, __HIP_MEMORY_SCOPE_AGENT);
            prs[tid] = __hip_atomic_load(&pred[tid], __ATOMIC_RELAXED, __HIP_MEMORY_SCOPE_AGENT);
        }
        __syncthreads();
        if (tid == 0) {
            float loop_loss[NLOOP], loop_acc[NLOOP], hasf[NLOOP];
            float n_has = 0.f, hms = 0.f, hcs = 0.f;
            for (int l = 0; l < NLOOP; ++l) {
                float cnt = 0.f, se = 0.f, sc = 0.f;
                for (int b = 0; b < BB; ++b) {
                    int cl = chain_lens[b];
                    int ti = l < cl - 1 ? l : cl - 1;
                    int tgt = chain_targets[b * NLOOP + ti];
                    int as = ans_starts[b];
                    bool valid = (as >= 1) && (as < LLEN) && (tgt < VV);
                    int idx = l * BB + b;
                    float ce = lzs[idx] - tgt_logit[idx];
                    float corr = (prs[idx] == tgt) ? 1.f : 0.f;
                    if (valid) {
                        cnt += 1.f; se += ce; sc += corr;
                        if (tgt == HALT) { hms += 1.f; hcs += corr; }
                    }
                }
                bool has = cnt > 0.f;
                hasf[l] = has ? 1.f : 0.f;
                n_has += hasf[l];
                float denom = cnt > 1.f ? cnt : 1.f;
                loop_loss[l] = has ? se / denom : 0.f;
                loop_acc[l]  = has ? sc / denom : 0.f;
            }
            float nn = n_has > 1.f ? n_has : 1.f;
            float avg_loss = 0.f, avg_acc = 0.f;
            for (int l = 0; l < NLOOP; ++l) {
                avg_loss += loop_loss[l] * hasf[l];
                avg_acc  += loop_acc[l]  * hasf[l];
            }
            avg_loss /= nn; avg_acc /= nn;
            int last_valid = NLOOP - 1;   // matches jnp.argmax on all-false reversed
            for (int l = NLOOP - 1; l >= 0; --l) if (hasf[l] > 0.f) { last_valid = l; break; }
            float ams = 0.f, aacc = 0.f;
            for (int l = 0; l < NLOOP; ++l) {
                float mask = (n_has > 1.f) ? (hasf[l] * ((l != last_valid) ? 1.f : 0.f)) : hasf[l];
                ams += mask; aacc += loop_acc[l] * mask;
            }
            float answer_acc = (ams > 0.f) ? (aacc / (ams > 1.f ? ams : 1.f)) : avg_acc;
            float halt_acc = (hms > 0.f) ? (hcs / (hms > 1.f ? hms : 1.f)) : 0.f;
            out[0] = avg_loss; out[1] = avg_acc; out[2] = answer_acc; out[3] = halt_acc;
        }
    }
}

extern "C" void kernel_launch(void* const* d_in, const int* in_sizes, int n_in,
                              void* d_out, int out_size, void* d_ws, size_t ws_size,
                              hipStream_t stream) {
    const float* x   = (const float*)d_in[0];
    const float* res = (const float*)d_in[1];
    const float* nw  = (const float*)d_in[2];
    const float* W   = (const float*)d_in[3];
    const int* ans   = (const int*)d_in[4];
    const int* ct    = (const int*)d_in[5];
    const int* cl    = (const int*)d_in[6];
    float* out = (float*)d_out;

    char* ws = (char*)d_ws;
    unsigned short* hbf = (unsigned short*)ws;                       // 96 KiB
    float* tgtl = (float*)(ws + 98304);                              // 256 B
    size_t off = 98560;
    float* pmax = (float*)(ws + off);  off += (size_t)64 * NBLK * 4;
    float* psum = (float*)(ws + off);  off += (size_t)64 * NBLK * 4;
    int*   parg = (int*)  (ws + off);  off += (size_t)64 * NBLK * 4;
    float* logZ = (float*)(ws + off);  off += 256;
    int*   pred = (int*)  (ws + off);  off += 256;
    unsigned int* counters = (unsigned int*)(ws + off); off += 256;

    k_prep<<<64, 256, 0, stream>>>(x, res, nw, W, ans, ct, cl, hbf, tgtl, counters);
    k_logits<<<NBLK, 256, 0, stream>>>(W, hbf, tgtl, ans, ct, cl,
                                       pmax, psum, parg, logZ, pred, counters, out);
}

// Round 12
// 58.317 us; speedup vs baseline: 3.0608x; 3.0608x over previous
//
#include <hip/hip_runtime.h>
#include <hip/hip_bf16.h>
#include <math.h>

#define NLOOP 8
#define BB 8
#define LLEN 2048
#define DD 768
#define VV 50288
#define HALT 50277
#define EPSF 1e-5f

#define BN 64
#define BKK 32
#define KSTEPS (DD / BKK)              // 24
#define NBLK ((VV + BN - 1) / BN)      // 786
#define PFD 4                          // KSTEPS % PFD == 0

typedef short bf16x8 __attribute__((ext_vector_type(8)));
typedef float f32x4 __attribute__((ext_vector_type(4)));

// lgkm-only barrier: ds ops drained, global loads stay in flight (counted vmcnt at use).
// A/B-verified R4->R5 (+6.4us vs __syncthreads).
#define LGKM_BARRIER() asm volatile("s_waitcnt lgkmcnt(0)\n\ts_barrier" ::: "memory")

__device__ __forceinline__ unsigned short f32_to_bf16(float f) {
    unsigned u = __builtin_bit_cast(unsigned, f);
    unsigned r = (u + 0x7FFFu + ((u >> 16) & 1u)) >> 16;
    return (unsigned short)r;
}

// ---------------- Kernel 1: gather + RMSNorm + target logits ----------------
__global__ __launch_bounds__(256) void k_prep(
    const float* __restrict__ x, const float* __restrict__ res,
    const float* __restrict__ nw, const float* __restrict__ W,
    const int* __restrict__ ans_starts, const int* __restrict__ chain_targets,
    const int* __restrict__ chain_lens,
    unsigned short* __restrict__ hbf, float* __restrict__ tgt_logit,
    unsigned int* __restrict__ counter)
{
    if (blockIdx.x == 0 && threadIdx.x == 0) *counter = 0u;   // for k_combine

    int lb = blockIdx.x, l = lb >> 3, b = lb & 7;
    int tid = threadIdx.x, lane = tid & 63, wave = tid >> 6;
    int as = ans_starts[b];
    int pos = as - 1;
    pos = pos < 0 ? 0 : (pos > LLEN - 1 ? LLEN - 1 : pos);
    size_t base = ((size_t)lb * LLEN + (size_t)pos) * DD;

    float hv[3];
    float ss = 0.f;
#pragma unroll
    for (int i = 0; i < 3; ++i) {
        int d = tid + i * 256;
        float v = x[base + d] + res[base + d];
        hv[i] = v;
        ss += v * v;
    }
#pragma unroll
    for (int off = 32; off; off >>= 1) ss += __shfl_down(ss, off);
    __shared__ float red[4];
    __shared__ float bc;
    if (lane == 0) red[wave] = ss;
    __syncthreads();
    if (tid == 0) bc = red[0] + red[1] + red[2] + red[3];
    __syncthreads();
    float rs = rsqrtf(bc / (float)DD + EPSF);

    int cl = chain_lens[b];
    int tix = l < cl - 1 ? l : cl - 1;
    int tgt = chain_targets[b * NLOOP + tix];
    bool tok = (tgt >= 0) && (tgt < VV);

    float dp = 0.f;
#pragma unroll
    for (int i = 0; i < 3; ++i) {
        int d = tid + i * 256;
        float h = hv[i] * rs * nw[d];
        hbf[(size_t)lb * DD + d] = f32_to_bf16(h);
        if (tok) dp += h * W[(size_t)tgt * DD + d];
    }
#pragma unroll
    for (int off = 32; off; off >>= 1) dp += __shfl_down(dp, off);
    __syncthreads();
    if (lane == 0) red[wave] = dp;
    __syncthreads();
    if (tid == 0) tgt_logit[lb] = red[0] + red[1] + red[2] + red[3];
}

// ---------------- Kernel 2: A-in-registers MFMA logits (R5 + swizzle) -------
// R5 trunk with conflict-free XOR-swizzled B-tile (verified R10/R11:
// SQ_LDS_BANK_CONFLICT -> 0, refcheck passed): row = 32 shorts (64B);
// write unit uw = j2^((r1>>1)&3), read unit ur = q^((c>>1)&3) -- each 8-lane
// phase covers all 32 banks on both write (b128) and read (b128).
// 4-deep counted-vmcnt register prefetch; lgkm-only barrier per K-step.
// Partials written TRANSPOSED: pmax[row * NBLK + blk].
__global__ __launch_bounds__(256) void k_logits(
    const float* __restrict__ W, const unsigned short* __restrict__ hbf,
    float* __restrict__ pmax, float* __restrict__ psum, int* __restrict__ parg)
{
    __shared__ unsigned short Bs[2][64 * 32];   // 4 KB per buffer, 64B rows

    int blk = blockIdx.x;
    int v0 = blk * BN;
    int tid = threadIdx.x;
    int wave = tid >> 6, lane = tid & 63, q = lane >> 4, c = lane & 15;

    // ---- A preload: h row (16*wave + c), k = ks*32 + q*8 + j (L2-hot) ----
    const unsigned short* Ap = hbf + (size_t)(16 * wave + c) * DD + q * 8;
    bf16x8 A[KSTEPS];
#pragma unroll
    for (int ks = 0; ks < KSTEPS; ++ks)
        A[ks] = *(const bf16x8*)(Ap + ks * BKK);

    // ---- B staging: thread (r1=tid>>2, j2=tid&3) loads row r1's 8 f32 ----
    int r1 = tid >> 2, j2 = tid & 3;
    int vB = v0 + r1;
    const float* gB = W + (size_t)(vB < VV ? vB : 0) * DD + j2 * 8;  // clamp; cols masked later

    f32x4 acc[4];
#pragma unroll
    for (int n = 0; n < 4; ++n) acc[n] = (f32x4){0.f, 0.f, 0.f, 0.f};

    const int uw = (j2 ^ ((r1 >> 1) & 3)) * 8;     // swizzled write unit (shorts)
    const int ur = (q ^ ((c >> 1) & 3)) * 8;       // swizzled read unit (shorts)

    auto stage_write = [&](int bufi, const f32x4& ra, const f32x4& rb) {
        bf16x8 v;
        v[0] = (short)f32_to_bf16(ra[0]); v[1] = (short)f32_to_bf16(ra[1]);
        v[2] = (short)f32_to_bf16(ra[2]); v[3] = (short)f32_to_bf16(ra[3]);
        v[4] = (short)f32_to_bf16(rb[0]); v[5] = (short)f32_to_bf16(rb[1]);
        v[6] = (short)f32_to_bf16(rb[2]); v[7] = (short)f32_to_bf16(rb[3]);
        *(bf16x8*)&Bs[bufi][r1 * 32 + uw] = v;
    };
    auto mfma_step = [&](int bufi, int ks) {
        bf16x8 f0 = *(const bf16x8*)&Bs[bufi][(c +  0) * 32 + ur];
        bf16x8 f1 = *(const bf16x8*)&Bs[bufi][(c + 16) * 32 + ur];
        bf16x8 f2 = *(const bf16x8*)&Bs[bufi][(c + 32) * 32 + ur];
        bf16x8 f3 = *(const bf16x8*)&Bs[bufi][(c + 48) * 32 + ur];
        acc[0] = __builtin_amdgcn_mfma_f32_16x16x32_bf16(A[ks], f0, acc[0], 0, 0, 0);
        acc[1] = __builtin_amdgcn_mfma_f32_16x16x32_bf16(A[ks], f1, acc[1], 0, 0, 0);
        acc[2] = __builtin_amdgcn_mfma_f32_16x16x32_bf16(A[ks], f2, acc[2], 0, 0, 0);
        acc[3] = __builtin_amdgcn_mfma_f32_16x16x32_bf16(A[ks], f3, acc[3], 0, 0, 0);
    };

    // 4-deep register pipeline (named sets, static indexing via full unroll)
    f32x4 pa[PFD], pb[PFD];
#pragma unroll
    for (int i = 0; i < PFD; ++i) {
        pa[i] = *(const f32x4*)(gB + i * BKK);
        pb[i] = *(const f32x4*)(gB + i * BKK + 4);
    }

#pragma unroll
    for (int ks = 0; ks < KSTEPS; ++ks) {          // fully unrolled: slots static
        const int slot = ks % PFD;
        const int bufi = ks & 1;
        stage_write(bufi, pa[slot], pb[slot]);
        LGKM_BARRIER();
        if (ks + PFD < KSTEPS) {
            pa[slot] = *(const f32x4*)(gB + (ks + PFD) * BKK);
            pb[slot] = *(const f32x4*)(gB + (ks + PFD) * BKK + 4);
        }
        mfma_step(bufi, ks);
    }

    // ---- wave-internal per-row max / argmax / sumexp over 64 block cols ----
    const float NEGINF = -__builtin_inff();
#pragma unroll
    for (int r = 0; r < 4; ++r) {
        float val = NEGINF; int idx = 0x7fffffff;
#pragma unroll
        for (int n = 0; n < 4; ++n) {
            int colg = v0 + 16 * n + c;
            float v = (colg < VV) ? acc[n][r] : NEGINF;
            if (v > val || (v == val && colg < idx)) { val = v; idx = colg; }
        }
#pragma unroll
        for (int off = 1; off < 16; off <<= 1) {
            float ov = __shfl_xor(val, off);
            int oi = __shfl_xor(idx, off);
            if (ov > val || (ov == val && oi < idx)) { val = ov; idx = oi; }
        }
        float M = val;          // all 16 lanes of the q-group hold the row max
        float e = 0.f;
#pragma unroll
        for (int n = 0; n < 4; ++n) {
            int colg = v0 + 16 * n + c;
            e += (colg < VV) ? __expf(acc[n][r] - M) : 0.f;
        }
#pragma unroll
        for (int off = 1; off < 16; off <<= 1) e += __shfl_xor(e, off);
        if (c == 0) {
            int row = 16 * wave + 4 * q + r;
            pmax[(size_t)row * NBLK + blk] = M;
            psum[(size_t)row * NBLK + blk] = e;
            parg[(size_t)row * NBLK + blk] = idx;
        }
    }
}

// ------- Kernel 3: parallel combine + fused last-block scalar epilogue ------
__global__ __launch_bounds__(256) void k_combine(
    const float* __restrict__ pmax, const float* __restrict__ psum,
    const int* __restrict__ parg, const float* __restrict__ tgt_logit,
    const int* __restrict__ ans_starts, const int* __restrict__ chain_targets,
    const int* __restrict__ chain_lens,
    float* __restrict__ logZ, int* __restrict__ pred,
    unsigned int* __restrict__ counter, float* __restrict__ out)
{
    int r = blockIdx.x;                 // row 0..63
    int tid = threadIdx.x;
    int wave = tid >> 6, lane = tid & 63;
    const float NEGINF = -__builtin_inff();

    const float* pm = pmax + (size_t)r * NBLK;
    const float* ps = psum + (size_t)r * NBLK;
    const int*   pa = parg + (size_t)r * NBLK;

    float M = NEGINF; int A_ = 0x7fffffff;
    for (int i = tid; i < NBLK; i += 256) {
        float m = pm[i];
        int a = pa[i];
        if (m > M || (m == M && a < A_)) { M = m; A_ = a; }
    }
#pragma unroll
    for (int off = 1; off < 64; off <<= 1) {
        float ov = __shfl_xor(M, off);
        int oa = __shfl_xor(A_, off);
        if (ov > M || (ov == M && oa < A_)) { M = ov; A_ = oa; }
    }
    __shared__ float sm[4]; __shared__ int sa[4]; __shared__ float ssum[4];
    __shared__ int lastflag;
    if (lane == 0) { sm[wave] = M; sa[wave] = A_; }
    __syncthreads();
    if (tid == 0) {
#pragma unroll
        for (int w = 1; w < 4; ++w)
            if (sm[w] > sm[0] || (sm[w] == sm[0] && sa[w] < sa[0])) { sm[0] = sm[w]; sa[0] = sa[w]; }
    }
    __syncthreads();
    float Mg = sm[0];

    float S = 0.f;
    for (int i = tid; i < NBLK; i += 256)
        S += ps[i] * __expf(pm[i] - Mg);
#pragma unroll
    for (int off = 1; off < 64; off <<= 1) S += __shfl_xor(S, off);
    if (lane == 0) ssum[wave] = S;
    __syncthreads();
    if (tid == 0) {
        float lz = Mg + logf(ssum[0] + ssum[1] + ssum[2] + ssum[3]);
        __hip_atomic_store(&logZ[r], lz, __ATOMIC_RELAXED, __HIP_MEMORY_SCOPE_AGENT);
        __hip_atomic_store(&pred[r], sa[0], __ATOMIC_RELAXED, __HIP_MEMORY_SCOPE_AGENT);
        __threadfence();                               // release
        unsigned int old = atomicAdd(counter, 1u);     // device-scope RMW
        lastflag = (old == 63u) ? 1 : 0;
    }
    __syncthreads();
    if (lastflag == 0) return;

    // ---- last block: scalar epilogue ----
    __threadfence();                                   // acquire
    __shared__ float lzs[64]; __shared__ int prs[64];
    if (tid < 64) {
        lzs[tid] = __hip_atomic_load(&logZ[tid], __ATOMIC_RELAXED, __HIP_MEMORY_SCOPE_AGENT);
        prs[tid] = __hip_atomic_load(&pred[tid], __ATOMIC_RELAXED, __HIP_MEMORY_SCOPE_AGENT);
    }
    __syncthreads();
    if (tid == 0) {
        float loop_loss[NLOOP], loop_acc[NLOOP], hasf[NLOOP];
        float n_has = 0.f, hms = 0.f, hcs = 0.f;
        for (int l = 0; l < NLOOP; ++l) {
            float cnt = 0.f, se = 0.f, sc = 0.f;
            for (int b = 0; b < BB; ++b) {
                int cl = chain_lens[b];
                int ti = l < cl - 1 ? l : cl - 1;
                int tgt = chain_targets[b * NLOOP + ti];
                int as = ans_starts[b];
                bool valid = (as >= 1) && (as < LLEN) && (tgt < VV);
                int idx = l * BB + b;
                float ce = lzs[idx] - tgt_logit[idx];
                float corr = (prs[idx] == tgt) ? 1.f : 0.f;
                if (valid) {
                    cnt += 1.f; se += ce; sc += corr;
                    if (tgt == HALT) { hms += 1.f; hcs += corr; }
                }
            }
            bool has = cnt > 0.f;
            hasf[l] = has ? 1.f : 0.f;
            n_has += hasf[l];
            float denom = cnt > 1.f ? cnt : 1.f;
            loop_loss[l] = has ? se / denom : 0.f;
            loop_acc[l]  = has ? sc / denom : 0.f;
        }
        float nn = n_has > 1.f ? n_has : 1.f;
        float avg_loss = 0.f, avg_acc = 0.f;
        for (int l = 0; l < NLOOP; ++l) {
            avg_loss += loop_loss[l] * hasf[l];
            avg_acc  += loop_acc[l]  * hasf[l];
        }
        avg_loss /= nn; avg_acc /= nn;
        int last_valid = NLOOP - 1;   // matches jnp.argmax on all-false reversed
        for (int l = NLOOP - 1; l >= 0; --l) if (hasf[l] > 0.f) { last_valid = l; break; }
        float ams = 0.f, aacc = 0.f;
        for (int l = 0; l < NLOOP; ++l) {
            float mask = (n_has > 1.f) ? (hasf[l] * ((l != last_valid) ? 1.f : 0.f)) : hasf[l];
            ams += mask; aacc += loop_acc[l] * mask;
        }
        float answer_acc = (ams > 0.f) ? (aacc / (ams > 1.f ? ams : 1.f)) : avg_acc;
        float halt_acc = (hms > 0.f) ? (hcs / (hms > 1.f ? hms : 1.f)) : 0.f;
        out[0] = avg_loss; out[1] = avg_acc; out[2] = answer_acc; out[3] = halt_acc;
    }
}

extern "C" void kernel_launch(void* const* d_in, const int* in_sizes, int n_in,
                              void* d_out, int out_size, void* d_ws, size_t ws_size,
                              hipStream_t stream) {
    const float* x   = (const float*)d_in[0];
    const float* res = (const float*)d_in[1];
    const float* nw  = (const float*)d_in[2];
    const float* W   = (const float*)d_in[3];
    const int* ans   = (const int*)d_in[4];
    const int* ct    = (const int*)d_in[5];
    const int* cl    = (const int*)d_in[6];
    float* out = (float*)d_out;

    char* ws = (char*)d_ws;
    unsigned short* hbf = (unsigned short*)ws;                       // 96 KiB
    float* tgtl = (float*)(ws + 98304);                              // 256 B
    size_t off = 98560;
    float* pmax = (float*)(ws + off);  off += (size_t)64 * NBLK * 4;
    float* psum = (float*)(ws + off);  off += (size_t)64 * NBLK * 4;
    int*   parg = (int*)  (ws + off);  off += (size_t)64 * NBLK * 4;
    float* logZ = (float*)(ws + off);  off += 256;
    int*   pred = (int*)  (ws + off);  off += 256;
    unsigned int* counter = (unsigned int*)(ws + off); off += 256;

    k_prep<<<64, 256, 0, stream>>>(x, res, nw, W, ans, ct, cl, hbf, tgtl, counter);
    k_logits<<<NBLK, 256, 0, stream>>>(W, hbf, pmax, psum, parg);
    k_combine<<<64, 256, 0, stream>>>(pmax, psum, parg, tgtl, ans, ct, cl,
                                      logZ, pred, counter, out);
}